// Round 3
// baseline (4369.429 us; speedup 1.0000x reference)
//
#include <hip/hip_runtime.h>
#include <hip/hip_bf16.h>

// Problem constants (from reference)
#define T_TOK 4096
#define DDIM  2048
#define HDIM  8192
#define ODIM  2048
#define NEXP  8
#define NACT  5

typedef __attribute__((ext_vector_type(8))) short short8;
typedef __attribute__((ext_vector_type(4))) float f32x4;

#define GLOBAL_AS __attribute__((address_space(1)))
#define LDS_AS    __attribute__((address_space(3)))

// ---------------------------------------------------------------------------
// fp32 -> bf16 conversion, 8 elems/thread, grid-stride
// ---------------------------------------------------------------------------
__global__ __launch_bounds__(256) void cvt_bf16(const float* __restrict__ s,
                                                __hip_bfloat16* __restrict__ d,
                                                long n) {
    long i = ((long)blockIdx.x * 256 + threadIdx.x) * 8;
    const long stride = (long)gridDim.x * 256 * 8;
    for (; i < n; i += stride) {
        float4 a = *(const float4*)(s + i);
        float4 b = *(const float4*)(s + i + 4);
        __hip_bfloat16 tmp[8];
        tmp[0] = __float2bfloat16(a.x); tmp[1] = __float2bfloat16(a.y);
        tmp[2] = __float2bfloat16(a.z); tmp[3] = __float2bfloat16(a.w);
        tmp[4] = __float2bfloat16(b.x); tmp[5] = __float2bfloat16(b.y);
        tmp[6] = __float2bfloat16(b.z); tmp[7] = __float2bfloat16(b.w);
        *(short8*)(d + i) = *(const short8*)tmp;
    }
}

// ---------------------------------------------------------------------------
// Gating: logits = x @ Wg^T + bg ; p = softmax(logits/e); top-5 mask; renorm.
// One block per token. Writes w [T,8] f32 straight into d_out tail.
// ---------------------------------------------------------------------------
__global__ __launch_bounds__(256) void gating_kernel(const float* __restrict__ x,
                                                     const float* __restrict__ Wg,
                                                     const float* __restrict__ bg,
                                                     float* __restrict__ wout) {
    const int t = blockIdx.x;
    const float* xr = x + (size_t)t * DDIM;
    float part[NEXP];
#pragma unroll
    for (int e = 0; e < NEXP; ++e) part[e] = 0.f;
    for (int d = threadIdx.x; d < DDIM; d += 256) {
        const float xv = xr[d];
#pragma unroll
        for (int e = 0; e < NEXP; ++e) part[e] += xv * Wg[e * DDIM + d];
    }
    __shared__ float red[256][NEXP];
#pragma unroll
    for (int e = 0; e < NEXP; ++e) red[threadIdx.x][e] = part[e];
    __syncthreads();
    for (int off = 128; off > 0; off >>= 1) {
        if ((int)threadIdx.x < off) {
#pragma unroll
            for (int e = 0; e < NEXP; ++e)
                red[threadIdx.x][e] += red[threadIdx.x + off][e];
        }
        __syncthreads();
    }
    if (threadIdx.x == 0) {
        const float invT = 1.0f / 2.718281828459045235f;
        float l[NEXP];
#pragma unroll
        for (int e = 0; e < NEXP; ++e) l[e] = (red[0][e] + bg[e]) * invT;
        float mx = l[0];
#pragma unroll
        for (int e = 1; e < NEXP; ++e) mx = fmaxf(mx, l[e]);
        float p[NEXP], s = 0.f;
#pragma unroll
        for (int e = 0; e < NEXP; ++e) { p[e] = __expf(l[e] - mx); s += p[e]; }
        const float invs = 1.0f / s;
#pragma unroll
        for (int e = 0; e < NEXP; ++e) p[e] *= invs;
        // top-NACT with jax.lax.top_k tie-break (lower index wins)
        float w[NEXP]; float ksum = 0.f;
#pragma unroll
        for (int i = 0; i < NEXP; ++i) {
            int cnt = 0;
#pragma unroll
            for (int j = 0; j < NEXP; ++j)
                if (p[j] > p[i] || (p[j] == p[i] && j < i)) cnt++;
            w[i] = (cnt < NACT) ? p[i] : 0.f;
            ksum += w[i];
        }
        const float inv = 1.0f / (ksum + 1e-8f);
#pragma unroll
        for (int e = 0; e < NEXP; ++e) wout[(size_t)t * NEXP + e] = w[e] * inv;
    }
}

// ---------------------------------------------------------------------------
// GEMM C = A[M,K] @ B[N,K]^T, bf16 inputs, fp32 accumulate. m97 structure:
// 128x128 tile, BK=32, 4 waves (2x2), 4x4 16x16x32 fragments per wave,
// global_load_lds width-16 staging, 2 barriers per K-step.
// EPI 0: hdn = bf16(relu(acc + bias[col]))
// EPI 1: out (=/+=) wgate[row*8+expert] * (acc + bias[col])   (fp32)
// ---------------------------------------------------------------------------
#define BM 128
#define BN 128
#define BK 32

template <int EPI>
__global__ __launch_bounds__(256) void gemm_bt(const __hip_bfloat16* __restrict__ A,
                                               const __hip_bfloat16* __restrict__ B,
                                               const float* __restrict__ bias,
                                               void* __restrict__ dst,
                                               const float* __restrict__ wgate,
                                               int M, int N, int K,
                                               int expert, int first) {
    __shared__ __align__(16) __hip_bfloat16 As[BM * BK];
    __shared__ __align__(16) __hip_bfloat16 Bs[BN * BK];

    const int t    = threadIdx.x;
    const int wave = t >> 6, lane = t & 63;
    const int wr = wave >> 1, wc = wave & 1;
    const int r16 = lane & 15, kg = lane >> 4;

    const long blockM = (long)blockIdx.y * BM;
    const long blockN = (long)blockIdx.x * BN;

    const int srow = t >> 2;          // 0..63
    const int scol = (t & 3) * 8;     // 0,8,16,24

    f32x4 acc[4][4];
#pragma unroll
    for (int m = 0; m < 4; ++m)
#pragma unroll
        for (int n = 0; n < 4; ++n) acc[m][n] = f32x4{0.f, 0.f, 0.f, 0.f};

    for (int k0 = 0; k0 < K; k0 += BK) {
#pragma unroll
        for (int i = 0; i < 2; ++i) {
            const __hip_bfloat16* ga = A + (blockM + srow + i * 64) * (long)K + k0 + scol;
            __builtin_amdgcn_global_load_lds((const GLOBAL_AS void*)ga,
                                             (LDS_AS void*)(As + i * 2048 + t * 8), 16, 0, 0);
            const __hip_bfloat16* gb = B + (blockN + srow + i * 64) * (long)K + k0 + scol;
            __builtin_amdgcn_global_load_lds((const GLOBAL_AS void*)gb,
                                             (LDS_AS void*)(Bs + i * 2048 + t * 8), 16, 0, 0);
        }
        __syncthreads();

        short8 af[4], bfr[4];
#pragma unroll
        for (int m = 0; m < 4; ++m)
            af[m] = *(const short8*)(As + (wr * 64 + m * 16 + r16) * BK + kg * 8);
#pragma unroll
        for (int n = 0; n < 4; ++n)
            bfr[n] = *(const short8*)(Bs + (wc * 64 + n * 16 + r16) * BK + kg * 8);
#pragma unroll
        for (int m = 0; m < 4; ++m)
#pragma unroll
            for (int n = 0; n < 4; ++n)
                acc[m][n] = __builtin_amdgcn_mfma_f32_16x16x32_bf16(af[m], bfr[n], acc[m][n], 0, 0, 0);
        __syncthreads();
    }

    const long grow0 = blockM + wr * 64;
    const long gcol0 = blockN + wc * 64;

    float bv[4];
#pragma unroll
    for (int n = 0; n < 4; ++n) bv[n] = bias[gcol0 + n * 16 + r16];

    if (EPI == 0) {
        __hip_bfloat16* D = (__hip_bfloat16*)dst;
#pragma unroll
        for (int m = 0; m < 4; ++m) {
            const long row = grow0 + m * 16 + kg * 4;
#pragma unroll
            for (int n = 0; n < 4; ++n) {
                const long col = gcol0 + n * 16 + r16;
#pragma unroll
                for (int j = 0; j < 4; ++j) {
                    float v = acc[m][n][j] + bv[n];
                    v = v > 0.f ? v : 0.f;
                    D[(row + j) * (long)N + col] = __float2bfloat16(v);
                }
            }
        }
    } else {
        float* D = (float*)dst;
#pragma unroll
        for (int m = 0; m < 4; ++m) {
            const long row = grow0 + m * 16 + kg * 4;
            float wv[4];
#pragma unroll
            for (int j = 0; j < 4; ++j) wv[j] = wgate[(row + j) * NEXP + expert];
#pragma unroll
            for (int n = 0; n < 4; ++n) {
                const long col = gcol0 + n * 16 + r16;
#pragma unroll
                for (int j = 0; j < 4; ++j) {
                    const float v = (acc[m][n][j] + bv[n]) * wv[j];
                    float* p = D + (row + j) * (long)N + col;
                    if (first) *p = v; else *p += v;
                }
            }
        }
    }
}

// ---------------------------------------------------------------------------
extern "C" void kernel_launch(void* const* d_in, const int* in_sizes, int n_in,
                              void* d_out, int out_size, void* d_ws, size_t ws_size,
                              hipStream_t stream) {
    const float* x  = (const float*)d_in[0];
    const float* W1 = (const float*)d_in[1];
    const float* b1 = (const float*)d_in[2];
    const float* W2 = (const float*)d_in[3];
    const float* b2 = (const float*)d_in[4];
    const float* Wg = (const float*)d_in[5];
    const float* bg = (const float*)d_in[6];

    float* out  = (float*)d_out;                       // [T,O]
    float* wout = out + (size_t)T_TOK * ODIM;          // [T,N]

    // Workspace layout (tight, 144 MB total):
    //   xbf  [T,D]  bf16 : 16 MB @ 0
    //   w1bf [H,D]  bf16 : 32 MB @ 16M
    //   w2bf [O,H]  bf16 : 32 MB @ 48M
    //   hdn  [T,H]  bf16 : 64 MB @ 80M
    char* ws = (char*)d_ws;
    __hip_bfloat16* xbf  = (__hip_bfloat16*)ws;
    __hip_bfloat16* w1bf = (__hip_bfloat16*)(ws + (16l << 20));
    __hip_bfloat16* w2bf = (__hip_bfloat16*)(ws + (48l << 20));
    __hip_bfloat16* hdn  = (__hip_bfloat16*)(ws + (80l << 20));

    const long nx  = (long)T_TOK * DDIM;
    const long nw1 = (long)HDIM * DDIM;
    const long nw2 = (long)ODIM * HDIM;

    cvt_bf16<<<2048, 256, 0, stream>>>(x, xbf, nx);
    gating_kernel<<<T_TOK, 256, 0, stream>>>(x, Wg, bg, wout);

    for (int n = 0; n < NEXP; ++n) {
        cvt_bf16<<<2048, 256, 0, stream>>>(W1 + (size_t)n * nw1, w1bf, nw1);
        gemm_bt<0><<<dim3(HDIM / BN, T_TOK / BM), 256, 0, stream>>>(
            xbf, w1bf, b1 + (size_t)n * HDIM, hdn, nullptr,
            T_TOK, HDIM, DDIM, n, 0);
        cvt_bf16<<<2048, 256, 0, stream>>>(W2 + (size_t)n * nw2, w2bf, nw2);
        gemm_bt<1><<<dim3(ODIM / BN, T_TOK / BM), 256, 0, stream>>>(
            hdn, w2bf, b2 + (size_t)n * ODIM, out, wout,
            T_TOK, ODIM, HDIM, n, (n == 0) ? 1 : 0);
    }
}